// Round 1
// baseline (448.283 us; speedup 1.0000x reference)
//
#include <hip/hip_runtime.h>
#include <stdint.h>

// ---------------------------------------------------------------------------
// Soft Decision Tree forward: DEPTH=10, INPUT_DIM=2048, OUTPUT_DIM=1000,
// NUM_INNER=1023, NUM_LEAF=1024, BATCH=8192.
// Outputs (flat concat): logits[8192*1000], mu[8192*1024], penalty[1],
// all_pp[8192*2047].
//
// R3: convert -> GEMM1(sigmoid) -> tree_expand (merged top+sub, pure
// mul+store walk) -> transpose (recomputes leaves; NOW also accumulates
// per-node num/den penalty partials, killing the 64 MB penalty pass)
// -> GEMM2 -> penalty_final (1 block).
// GEMMs: BK 32->64 (half the barrier-drain events) with XOR-swizzled
// staging source + swizzled ds_read (2-way banks instead of 16-way).
// ---------------------------------------------------------------------------

typedef short bf16x8 __attribute__((ext_vector_type(8)));
typedef float f32x4  __attribute__((ext_vector_type(4)));

#define ASG __attribute__((address_space(1)))
#define ASL __attribute__((address_space(3)))

__device__ __forceinline__ void gl_lds16(const void* g, void* l) {
  // async global->LDS, 16B per lane; LDS dest is wave-uniform base + lane*16
  __builtin_amdgcn_global_load_lds((ASG void*)(uintptr_t)g, (ASL void*)l, 16, 0, 0);
}

__device__ __forceinline__ unsigned short f2bf(float x) {
  union { float f; unsigned u; } v; v.f = x;
  unsigned r = v.u + 0x7FFFu + ((v.u >> 16) & 1u);  // RNE
  return (unsigned short)(r >> 16);
}

// ---------------------------------------------------------------------------
// K0: conversions. Xbf (8192x2048 bf16), Wbf (1024x2048 bf16, row 1023 = 0),
// bias[1024] (W_inner col 0), Wlbf (1024x1024 bf16, rows >=1000 zero).
// Also zeros the penalty slot.
// ---------------------------------------------------------------------------
__global__ __launch_bounds__(256) void convert_kernel(
    const float* __restrict__ X, const float* __restrict__ Wi,
    const float* __restrict__ Wl, unsigned short* __restrict__ Xbf,
    unsigned short* __restrict__ Wbf, unsigned short* __restrict__ Wlbf,
    float* __restrict__ bias, float* __restrict__ pen)
{
  const int tid = blockIdx.x * 256 + threadIdx.x;
  const int stride = gridDim.x * 256;

  const float4* X4 = (const float4*)X;
  ushort4* Xb4 = (ushort4*)Xbf;
  for (int i = tid; i < (8192 * 2048) / 4; i += stride) {
    float4 v = X4[i];
    ushort4 o;
    o.x = f2bf(v.x); o.y = f2bf(v.y); o.z = f2bf(v.z); o.w = f2bf(v.w);
    Xb4[i] = o;
  }
  for (int i = tid; i < 1024 * 2048; i += stride) {
    int t = i >> 11, k = i & 2047;
    Wbf[i] = (t < 1023) ? f2bf(Wi[t * 2049 + 1 + k]) : (unsigned short)0;
  }
  for (int i = tid; i < 1024 * 1024; i += stride) {
    Wlbf[i] = (i < 1000 * 1024) ? f2bf(Wl[i]) : (unsigned short)0;
  }
  if (tid < 1024) bias[tid] = (tid < 1023) ? Wi[tid * 2049] : 0.0f;
  if (tid == 0) *pen = 0.0f;
}

// ---------------------------------------------------------------------------
// bf16 NT GEMM (m97 structure, BK=64): C[m][n] = sum_k A[m][k]*B[n][k].
// 128x128 tile, BK=64, 4 waves of 4x4 16x16x32 MFMA (2 k-subwindows).
// Staging: global_load_lds with pre-swizzled SOURCE slot (slot ^= row&7);
// ds_read applies the same XOR -> 2-way banks (free) instead of 16-way.
// EPI=1: C = sigmoid(acc + bias[m]), unconditional store (GEMM1 -> p_t).
// EPI=0: plain store masked to n < nmax (GEMM2 -> logits).
// ---------------------------------------------------------------------------
template <int EPI>
__global__ __launch_bounds__(256) void gemm_bt(
    const unsigned short* __restrict__ A, const unsigned short* __restrict__ B,
    float* __restrict__ C, int K, int ldc, int nmax,
    const float* __restrict__ bias)
{
  __shared__ __align__(16) unsigned short sA[128 * 64];
  __shared__ __align__(16) unsigned short sB[128 * 64];

  const int tid  = threadIdx.x;
  const int lane = tid & 63;
  const int wv   = tid >> 6;
  const int wm   = (wv >> 1) * 64;
  const int wn   = (wv & 1) * 64;
  const int m0   = blockIdx.y * 128;
  const int n0   = blockIdx.x * 128;
  const int lr   = lane & 15;
  const int hi   = lane >> 4;

  f32x4 acc[4][4] = {};

  // staging geometry: 4 calls each for A/B; call c covers rows c*32..c*32+31.
  // lane -> (row chunk>>3, 16B slot chunk&7); source slot swizzled by row&7
  // so that linear LDS + XOR'd read are conflict-free (both-sides rule).
  const int chunk = wv * 64 + lane;             // 0..255
  const int crow  = chunk >> 3;                 // 0..31
  const int sl    = (chunk & 7) ^ (crow & 7);   // swizzled source slot
  const unsigned short* ga = A + (size_t)(m0 + crow) * K + sl * 8;
  const unsigned short* gb = B + (size_t)(n0 + crow) * K + sl * 8;
  unsigned short* sa = sA + wv * 512;           // wave-uniform LDS base
  unsigned short* sb = sB + wv * 512;
  const size_t rstep = (size_t)32 * K;          // 32 rows per staging call

  for (int k0 = 0; k0 < K; k0 += 64) {
    __syncthreads();
#pragma unroll
    for (int c = 0; c < 4; ++c) {
      gl_lds16(ga + k0 + c * rstep, sa + c * 2048);
      gl_lds16(gb + k0 + c * rstep, sb + c * 2048);
    }
    __syncthreads();

#pragma unroll
    for (int kk = 0; kk < 2; ++kk) {
      bf16x8 af[4], bfv[4];
#pragma unroll
      for (int i = 0; i < 4; ++i) {
        const int row = wm + i * 16 + lr;
        const int sp  = (hi + kk * 4) ^ (row & 7);   // physical slot
        af[i] = *(const bf16x8*)&sA[row * 64 + sp * 8];
      }
#pragma unroll
      for (int i = 0; i < 4; ++i) {
        const int row = wn + i * 16 + lr;
        const int sp  = (hi + kk * 4) ^ (row & 7);
        bfv[i] = *(const bf16x8*)&sB[row * 64 + sp * 8];
      }
#pragma unroll
      for (int mi = 0; mi < 4; ++mi)
#pragma unroll
        for (int ni = 0; ni < 4; ++ni)
          acc[mi][ni] = __builtin_amdgcn_mfma_f32_16x16x32_bf16(
              af[mi], bfv[ni], acc[mi][ni], 0, 0, 0);
    }
  }

  // epilogue: D[m][n], m = (lane>>4)*4 + r, n = lane&15
#pragma unroll
  for (int mi = 0; mi < 4; ++mi) {
#pragma unroll
    for (int ni = 0; ni < 4; ++ni) {
      const int mbase = m0 + wm + mi * 16 + (lane >> 4) * 4;
      const int n = n0 + wn + ni * 16 + lr;
#pragma unroll
      for (int r = 0; r < 4; ++r) {
        const int m = mbase + r;
        float v = acc[mi][ni][r];
        if (EPI == 1) {
          v += bias[m];
          v = 1.0f / (1.0f + __expf(-v));
          C[(size_t)m * ldc + n] = v;
        } else {
          if (n < nmax) C[(size_t)m * ldc + n] = v;
        }
      }
    }
  }
}

// ---------------------------------------------------------------------------
// Tree expansion over INNER nodes only (levels 0..9), transposed layout
// app_t[node][batch], heap-ordered. Pure mul+store walk — no reductions.
// Merged: blocks with subtree==0 also walk the top 31 nodes (levels 0..4).
// Block 0 additionally zeros the num/den penalty accumulators.
// ---------------------------------------------------------------------------
template <int LVL, int MAXLVL>
__device__ __forceinline__ void walk(unsigned t, float mu,
                                     const float* __restrict__ p_t,
                                     float* __restrict__ app, unsigned b)
{
  app[t * 8192u + b] = mu;
  if constexpr (LVL < MAXLVL) {
    float p = p_t[t * 8192u + b];
    walk<LVL + 1, MAXLVL>(2u * t + 1u, mu * (1.0f - p), p_t, app, b);
    walk<LVL + 1, MAXLVL>(2u * t + 2u, mu * p, p_t, app, b);
  }
}

__global__ __launch_bounds__(256) void tree_expand(const float* __restrict__ p_t,
                                                   float* __restrict__ app,
                                                   float* __restrict__ nd)
{
  if (blockIdx.x == 0) {
    for (int i = threadIdx.x; i < 2048; i += 256) nd[i] = 0.0f;
  }
  unsigned b = (blockIdx.x & 31u) * 256u + threadIdx.x;  // 0..8191
  unsigned s = blockIdx.x >> 5;                          // subtree 0..31
  if (s == 0) walk<0, 4>(0u, 1.0f, p_t, app, b);         // nodes 0..30
  unsigned t0 = 31u + s;                                 // level-5 root
  // recompute root mu from the 5 ancestors (rows are L2-resident)
  float mu = 1.0f;
  unsigned a = t0;
#pragma unroll
  for (int l = 0; l < 5; ++l) {
    unsigned par = (a - 1u) >> 1;
    float p = p_t[par * 8192u + b];
    mu *= (a & 1u) ? (1.0f - p) : p;   // odd = left child = (1-p)
    a = par;
  }
  walk<5, 9>(t0, mu, p_t, app, b);     // nodes 31..1022
}

// ---------------------------------------------------------------------------
// Transpose app_t (inner nodes) -> all_pp (8192x2047); leaves (t>=1023)
// recomputed from parent mu/p and additionally written to mu (8192x1024)
// and mu_bf (bf16, GEMM2 A operand). Fused penalty partials: per inner
// node t, atomically accumulate num[t]=sum_b p*mu, den[t]=sum_b mu.
// ---------------------------------------------------------------------------
__global__ __launch_bounds__(256) void transpose_out(
    const float* __restrict__ app_t, const float* __restrict__ p_t,
    float* __restrict__ all_pp, float* __restrict__ mu_out,
    unsigned short* __restrict__ mu_bf, float* __restrict__ num,
    float* __restrict__ den)
{
  __shared__ float tile[32][33];
  const int b0 = blockIdx.x * 32;
  const int t0 = blockIdx.y * 32;
  const int tx = threadIdx.x;  // 0..31
  const int ty = threadIdx.y;  // 0..7

#pragma unroll
  for (int r = 0; r < 4; ++r) {
    int t = t0 + ty + r * 8;
    float v = 0.0f;
    if (t < 1023) {
      v = app_t[(size_t)t * 8192 + b0 + tx];
      float p = p_t[(size_t)t * 8192 + b0 + tx];
      // 32-lane row reduce (t is uniform within the 32-lane subgroup)
      float np = v * p, dn = v;
#pragma unroll
      for (int o = 16; o; o >>= 1) {
        np += __shfl_down(np, o, 32);
        dn += __shfl_down(dn, o, 32);
      }
      if (tx == 0) {
        atomicAdd(&num[t], np);
        atomicAdd(&den[t], dn);
      }
    } else if (t < 2047) {
      int u = (t - 1) >> 1;                       // parent (511..1022)
      float m = app_t[(size_t)u * 8192 + b0 + tx];
      float p = p_t[(size_t)u * 8192 + b0 + tx];
      v = (t & 1) ? m * (1.0f - p) : m * p;
    }
    tile[ty + r * 8][tx] = v;
  }
  __syncthreads();
#pragma unroll
  for (int r = 0; r < 4; ++r) {
    int b = b0 + ty + r * 8;
    int t = t0 + tx;
    if (t < 2047) {
      float v = tile[tx][ty + r * 8];
      all_pp[(size_t)b * 2047 + t] = v;
      if (t >= 1023) {
        int l = t - 1023;
        mu_out[(size_t)b * 1024 + l] = v;
        mu_bf[(size_t)b * 1024 + l] = f2bf(v);
      }
    }
  }
}

// ---------------------------------------------------------------------------
// Penalty finalize: alpha[t] = num[t]/den[t]; pen_t = log(a)+log(1-a)
// (non-finite -> 0); penalty = -sum 0.5*2^-lvl * pen_t. One block.
// ---------------------------------------------------------------------------
__global__ __launch_bounds__(1024) void penalty_final(
    const float* __restrict__ num, const float* __restrict__ den,
    float* __restrict__ pen)
{
  const int t = threadIdx.x;
  float c = 0.0f;
  if (t < 1023) {
    float a = num[t] / den[t];
    float lg = __logf(a) + __logf(1.0f - a);
    if (!(lg > -1e30f && lg < 1e30f)) lg = 0.0f;  // NaN / +-inf -> 0
    int lvl = 31 - __clz(t + 1);
    c = -0.5f * (1.0f / (float)(1 << lvl)) * lg;
  }
#pragma unroll
  for (int o = 32; o; o >>= 1) c += __shfl_down(c, o);
  __shared__ float red[16];
  const int wv = threadIdx.x >> 6;
  if ((threadIdx.x & 63) == 0) red[wv] = c;
  __syncthreads();
  if (threadIdx.x == 0) {
    float s = 0.0f;
#pragma unroll
    for (int i = 0; i < 16; ++i) s += red[i];
    *pen = s;
  }
}

// ---------------------------------------------------------------------------
extern "C" void kernel_launch(void* const* d_in, const int* in_sizes, int n_in,
                              void* d_out, int out_size, void* d_ws,
                              size_t ws_size, hipStream_t stream)
{
  const float* X  = (const float*)d_in[0];  // 8192x2048
  const float* Wi = (const float*)d_in[1];  // 1023x2049
  const float* Wl = (const float*)d_in[2];  // 1000x1024
  float* out = (float*)d_out;

  char* ws = (char*)d_ws;
  // workspace layout (bytes):
  float* p_t            = (float*)(ws + 0);                  // 32 MB
  unsigned short* Xbf   = (unsigned short*)(ws + 33554432);  // 32 MB
  float* app_t          = (float*)(ws + 33554432);           // overlay, 32 MB
  unsigned short* mu_bf = (unsigned short*)(ws + 67108864);  // 16 MB
  unsigned short* Wbf   = (unsigned short*)(ws + 83886080);  // 4 MB
  unsigned short* Wlbf  = (unsigned short*)(ws + 88080384);  // 2 MB
  float* bias           = (float*)(ws + 90177536);           // 4 KB
  // num/den (8 KB) overlay Wbf — Wbf is dead after GEMM1; zeroed by
  // tree_expand (which runs after GEMM1, before transpose_out).
  float* nd             = (float*)(ws + 83886080);

  float* logits = out;                 // 8192*1000
  float* mu_out = out + 8192000;       // 8192*1024
  float* pen    = out + 16580608;      // 1
  float* all_pp = out + 16580609;      // 8192*2047

  convert_kernel<<<1024, 256, 0, stream>>>(X, Wi, Wl, Xbf, Wbf, Wlbf, bias, pen);
  // GEMM1: M=nodes(1024), N=batch(8192), K=2048 -> p_t[t][b] = sigmoid(.+bias)
  gemm_bt<1><<<dim3(64, 8), 256, 0, stream>>>(Wbf, Xbf, p_t, 2048, 8192, 8192, bias);
  tree_expand<<<1024, 256, 0, stream>>>(p_t, app_t, nd);
  transpose_out<<<dim3(256, 64), dim3(32, 8), 0, stream>>>(app_t, p_t, all_pp,
                                                           mu_out, mu_bf,
                                                           nd, nd + 1024);
  // GEMM2: M=batch(8192), N=leafout(1024, mask 1000), K=1024 -> logits
  gemm_bt<0><<<dim3(8, 64), 256, 0, stream>>>(mu_bf, Wlbf, logits, 1024, 1000, 1000, nullptr);
  penalty_final<<<1, 1024, 0, stream>>>(nd, nd + 1024, pen);
}

// Round 2
// 377.721 us; speedup vs baseline: 1.1868x; 1.1868x over previous
//
#include <hip/hip_runtime.h>
#include <stdint.h>

// ---------------------------------------------------------------------------
// Soft Decision Tree forward: DEPTH=10, INPUT_DIM=2048, OUTPUT_DIM=1000,
// NUM_INNER=1023, NUM_LEAF=1024, BATCH=8192.
// Outputs (flat concat): logits[8192*1000], mu[8192*1024], penalty[1],
// all_pp[8192*2047].
//
// R4: convert -> GEMM1(sigmoid, BK=32 proven) -> tree_expand (merged top+sub)
// -> transpose v2 (64t x 128b tile, float2 row loads = 1KB/wave-instr,
//    wave-wide 256B row stores, LDS [64][129] conflict-free) -> GEMM2
// -> penalty_nodes (separate streaming pass, L3-warm, ~12 us).
// R3's fused penalty (524K contended atomics, +85 us) reverted.
// ---------------------------------------------------------------------------

typedef short bf16x8 __attribute__((ext_vector_type(8)));
typedef float f32x4  __attribute__((ext_vector_type(4)));

#define ASG __attribute__((address_space(1)))
#define ASL __attribute__((address_space(3)))

__device__ __forceinline__ void gl_lds16(const void* g, void* l) {
  // async global->LDS, 16B per lane; LDS dest is wave-uniform base + lane*16
  __builtin_amdgcn_global_load_lds((ASG void*)(uintptr_t)g, (ASL void*)l, 16, 0, 0);
}

__device__ __forceinline__ unsigned short f2bf(float x) {
  union { float f; unsigned u; } v; v.f = x;
  unsigned r = v.u + 0x7FFFu + ((v.u >> 16) & 1u);  // RNE
  return (unsigned short)(r >> 16);
}

// ---------------------------------------------------------------------------
// K0: conversions. Xbf (8192x2048 bf16), Wbf (1024x2048 bf16, row 1023 = 0),
// bias[1024] (W_inner col 0), Wlbf (1024x1024 bf16, rows >=1000 zero).
// Also zeros the penalty slot.
// ---------------------------------------------------------------------------
__global__ __launch_bounds__(256) void convert_kernel(
    const float* __restrict__ X, const float* __restrict__ Wi,
    const float* __restrict__ Wl, unsigned short* __restrict__ Xbf,
    unsigned short* __restrict__ Wbf, unsigned short* __restrict__ Wlbf,
    float* __restrict__ bias, float* __restrict__ pen)
{
  const int tid = blockIdx.x * 256 + threadIdx.x;
  const int stride = gridDim.x * 256;

  const float4* X4 = (const float4*)X;
  ushort4* Xb4 = (ushort4*)Xbf;
  for (int i = tid; i < (8192 * 2048) / 4; i += stride) {
    float4 v = X4[i];
    ushort4 o;
    o.x = f2bf(v.x); o.y = f2bf(v.y); o.z = f2bf(v.z); o.w = f2bf(v.w);
    Xb4[i] = o;
  }
  for (int i = tid; i < 1024 * 2048; i += stride) {
    int t = i >> 11, k = i & 2047;
    Wbf[i] = (t < 1023) ? f2bf(Wi[t * 2049 + 1 + k]) : (unsigned short)0;
  }
  for (int i = tid; i < 1024 * 1024; i += stride) {
    Wlbf[i] = (i < 1000 * 1024) ? f2bf(Wl[i]) : (unsigned short)0;
  }
  if (tid < 1024) bias[tid] = (tid < 1023) ? Wi[tid * 2049] : 0.0f;
  if (tid == 0) *pen = 0.0f;
}

// ---------------------------------------------------------------------------
// bf16 NT GEMM (m97 structure): C[m][n] = sum_k A[m][k]*B[n][k].
// 128x128 tile, BK=32, 4 waves of 4x4 16x16x32 MFMA.  (R2-proven version.)
// EPI=1: C = sigmoid(acc + bias[m]), unconditional store (GEMM1 -> p_t).
// EPI=0: plain store masked to n < nmax (GEMM2 -> logits).
// ---------------------------------------------------------------------------
template <int EPI>
__global__ __launch_bounds__(256) void gemm_bt(
    const unsigned short* __restrict__ A, const unsigned short* __restrict__ B,
    float* __restrict__ C, int K, int ldc, int nmax,
    const float* __restrict__ bias)
{
  __shared__ __align__(16) unsigned short sA[128 * 32];
  __shared__ __align__(16) unsigned short sB[128 * 32];

  const int tid  = threadIdx.x;
  const int lane = tid & 63;
  const int wv   = tid >> 6;
  const int wm   = (wv >> 1) * 64;
  const int wn   = (wv & 1) * 64;
  const int m0   = blockIdx.y * 128;
  const int n0   = blockIdx.x * 128;
  const int lr   = lane & 15;
  const int lk   = (lane >> 4) * 8;

  f32x4 acc[4][4] = {};

  const int chunk0 = wv * 64 + lane;
  const int crow   = chunk0 >> 2;         // 0..63
  const int coff   = (chunk0 & 3) * 8;    // element offset within row
  const unsigned short* ga0 = A + (size_t)(m0 + crow) * K + coff;
  const unsigned short* ga1 = A + (size_t)(m0 + crow + 64) * K + coff;
  const unsigned short* gb0 = B + (size_t)(n0 + crow) * K + coff;
  const unsigned short* gb1 = B + (size_t)(n0 + crow + 64) * K + coff;
  unsigned short* sa0 = sA + (wv * 64) * 8;          // wave-uniform LDS base
  unsigned short* sa1 = sA + (256 + wv * 64) * 8;
  unsigned short* sb0 = sB + (wv * 64) * 8;
  unsigned short* sb1 = sB + (256 + wv * 64) * 8;

  for (int k0 = 0; k0 < K; k0 += 32) {
    __syncthreads();
    gl_lds16(ga0 + k0, sa0);
    gl_lds16(ga1 + k0, sa1);
    gl_lds16(gb0 + k0, sb0);
    gl_lds16(gb1 + k0, sb1);
    __syncthreads();

    bf16x8 af[4], bfv[4];
#pragma unroll
    for (int i = 0; i < 4; ++i)
      af[i] = *(const bf16x8*)&sA[(wm + i * 16 + lr) * 32 + lk];
#pragma unroll
    for (int i = 0; i < 4; ++i)
      bfv[i] = *(const bf16x8*)&sB[(wn + i * 16 + lr) * 32 + lk];
#pragma unroll
    for (int mi = 0; mi < 4; ++mi)
#pragma unroll
      for (int ni = 0; ni < 4; ++ni)
        acc[mi][ni] = __builtin_amdgcn_mfma_f32_16x16x32_bf16(
            af[mi], bfv[ni], acc[mi][ni], 0, 0, 0);
  }

  // epilogue: D[m][n], m = (lane>>4)*4 + r, n = lane&15
#pragma unroll
  for (int mi = 0; mi < 4; ++mi) {
#pragma unroll
    for (int ni = 0; ni < 4; ++ni) {
      const int mbase = m0 + wm + mi * 16 + (lane >> 4) * 4;
      const int n = n0 + wn + ni * 16 + lr;
#pragma unroll
      for (int r = 0; r < 4; ++r) {
        const int m = mbase + r;
        float v = acc[mi][ni][r];
        if (EPI == 1) {
          v += bias[m];
          v = 1.0f / (1.0f + __expf(-v));
          C[(size_t)m * ldc + n] = v;
        } else {
          if (n < nmax) C[(size_t)m * ldc + n] = v;
        }
      }
    }
  }
}

// ---------------------------------------------------------------------------
// Tree expansion over INNER nodes only (levels 0..9), transposed layout
// app_t[node][batch], heap-ordered. Pure mul+store walk — no reductions.
// Merged: blocks with subtree==0 also walk the top 31 nodes (levels 0..4).
// ---------------------------------------------------------------------------
template <int LVL, int MAXLVL>
__device__ __forceinline__ void walk(unsigned t, float mu,
                                     const float* __restrict__ p_t,
                                     float* __restrict__ app, unsigned b)
{
  app[t * 8192u + b] = mu;
  if constexpr (LVL < MAXLVL) {
    float p = p_t[t * 8192u + b];
    walk<LVL + 1, MAXLVL>(2u * t + 1u, mu * (1.0f - p), p_t, app, b);
    walk<LVL + 1, MAXLVL>(2u * t + 2u, mu * p, p_t, app, b);
  }
}

__global__ __launch_bounds__(256) void tree_expand(const float* __restrict__ p_t,
                                                   float* __restrict__ app)
{
  unsigned b = (blockIdx.x & 31u) * 256u + threadIdx.x;  // 0..8191
  unsigned s = blockIdx.x >> 5;                          // subtree 0..31
  if (s == 0) walk<0, 4>(0u, 1.0f, p_t, app, b);         // nodes 0..30
  unsigned t0 = 31u + s;                                 // level-5 root
  // recompute root mu from the 5 ancestors (rows are L2-resident)
  float mu = 1.0f;
  unsigned a = t0;
#pragma unroll
  for (int l = 0; l < 5; ++l) {
    unsigned par = (a - 1u) >> 1;
    float p = p_t[par * 8192u + b];
    mu *= (a & 1u) ? (1.0f - p) : p;   // odd = left child = (1-p)
    a = par;
  }
  walk<5, 9>(t0, mu, p_t, app, b);     // nodes 31..1022
}

// ---------------------------------------------------------------------------
// Transpose v2: app_t (inner nodes, t-major) -> all_pp (8192x2047, b-major);
// leaves (t>=1023) recomputed from parent mu/p rows and additionally written
// to mu_out (8192x1024) and mu_bf (bf16, GEMM2 A operand).
// Tile: 64 t x 128 b. Load: one wave per row, float2/lane = 1KB contiguous
// per instruction. Store: one wave per b-row, lane covers 64 t = 256B
// contiguous. LDS [64][129]: column reads stride 129 (conflict-free).
// All row-type branches are wave-uniform.
// ---------------------------------------------------------------------------
__global__ __launch_bounds__(256) void transpose_out(
    const float* __restrict__ app_t, const float* __restrict__ p_t,
    float* __restrict__ all_pp, float* __restrict__ mu_out,
    unsigned short* __restrict__ mu_bf)
{
  __shared__ float tile[64][129];
  const int b0   = blockIdx.x * 128;
  const int t0   = blockIdx.y * 64;
  const int lane = threadIdx.x & 63;
  const int wv   = threadIdx.x >> 6;  // 0..3

  // ---- load phase: 16 passes x 4 waves, one t-row per wave
#pragma unroll 4
  for (int ps = 0; ps < 16; ++ps) {
    const int r = ps * 4 + wv;        // 0..63 (wave-uniform)
    const int t = t0 + r;
    float2 v;
    if (t < 1023) {
      v = *(const float2*)&app_t[(size_t)t * 8192 + b0 + lane * 2];
    } else if (t < 2047) {
      const int u = (t - 1) >> 1;     // parent 511..1022
      const float2 m = *(const float2*)&app_t[(size_t)u * 8192 + b0 + lane * 2];
      const float2 p = *(const float2*)&p_t[(size_t)u * 8192 + b0 + lane * 2];
      if (t & 1) { v.x = m.x * (1.0f - p.x); v.y = m.y * (1.0f - p.y); }
      else       { v.x = m.x * p.x;          v.y = m.y * p.y; }
    } else {
      v.x = 0.0f; v.y = 0.0f;         // t == 2047 pad row
    }
    tile[r][lane * 2]     = v.x;
    tile[r][lane * 2 + 1] = v.y;
  }
  __syncthreads();

  // ---- store phase: 32 passes x 4 waves, one b-row per wave; lane = t
  const int t = t0 + lane;
  const bool tin  = (t < 2047);
  const bool leaf = (t >= 1023) && tin;
#pragma unroll 4
  for (int ps = 0; ps < 32; ++ps) {
    const int bl = ps * 4 + wv;       // 0..127 (wave-uniform)
    const int b  = b0 + bl;
    const float v = tile[lane][bl];   // stride-129 column read, no conflicts
    if (tin) {
      all_pp[(size_t)b * 2047 + t] = v;
      if (leaf) {
        const int l = t - 1023;
        mu_out[(size_t)b * 1024 + l] = v;
        mu_bf[(size_t)b * 1024 + l]  = f2bf(v);
      }
    }
  }
}

// ---------------------------------------------------------------------------
// Penalty: per inner node t, alpha = sum_b(p*mu)/sum_b(mu);
// pen_t = log(a)+log(1-a) (non-finite -> 0); penalty -= 0.5*2^-lvl * pen_t.
// Coalesced streaming over t-major rows (L3-warm); one atomic per block.
// ---------------------------------------------------------------------------
__global__ __launch_bounds__(256) void penalty_nodes(
    const float* __restrict__ app_t, const float* __restrict__ p_t,
    float* __restrict__ pen)
{
  const int t = blockIdx.x;  // 0..1022
  const float* mu = app_t + (size_t)t * 8192;
  const float* pp = p_t + (size_t)t * 8192;
  float num = 0.0f, den = 0.0f;
  for (int b = threadIdx.x; b < 8192; b += 256) {
    float m = mu[b];
    num += m * pp[b];
    den += m;
  }
#pragma unroll
  for (int o = 32; o; o >>= 1) {
    num += __shfl_down(num, o);
    den += __shfl_down(den, o);
  }
  __shared__ float sn[4], sd[4];
  if ((threadIdx.x & 63) == 0) {
    sn[threadIdx.x >> 6] = num;
    sd[threadIdx.x >> 6] = den;
  }
  __syncthreads();
  if (threadIdx.x == 0) {
    num = sn[0] + sn[1] + sn[2] + sn[3];
    den = sd[0] + sd[1] + sd[2] + sd[3];
    float a = num / den;
    float lg = __logf(a) + __logf(1.0f - a);
    if (!(lg > -1e30f && lg < 1e30f)) lg = 0.0f;  // NaN / +-inf -> 0
    int lvl = 31 - __clz(t + 1);
    float contrib = -0.5f * (1.0f / (float)(1 << lvl)) * lg;
    atomicAdd(pen, contrib);
  }
}

// ---------------------------------------------------------------------------
extern "C" void kernel_launch(void* const* d_in, const int* in_sizes, int n_in,
                              void* d_out, int out_size, void* d_ws,
                              size_t ws_size, hipStream_t stream)
{
  const float* X  = (const float*)d_in[0];  // 8192x2048
  const float* Wi = (const float*)d_in[1];  // 1023x2049
  const float* Wl = (const float*)d_in[2];  // 1000x1024
  float* out = (float*)d_out;

  char* ws = (char*)d_ws;
  // workspace layout (bytes):
  float* p_t            = (float*)(ws + 0);                  // 32 MB
  unsigned short* Xbf   = (unsigned short*)(ws + 33554432);  // 32 MB
  float* app_t          = (float*)(ws + 33554432);           // overlay, 32 MB
  unsigned short* mu_bf = (unsigned short*)(ws + 67108864);  // 16 MB
  unsigned short* Wbf   = (unsigned short*)(ws + 83886080);  // 4 MB
  unsigned short* Wlbf  = (unsigned short*)(ws + 88080384);  // 2 MB
  float* bias           = (float*)(ws + 90177536);           // 4 KB

  float* logits = out;                 // 8192*1000
  float* mu_out = out + 8192000;       // 8192*1024
  float* pen    = out + 16580608;      // 1
  float* all_pp = out + 16580609;      // 8192*2047

  convert_kernel<<<1024, 256, 0, stream>>>(X, Wi, Wl, Xbf, Wbf, Wlbf, bias, pen);
  // GEMM1: M=nodes(1024), N=batch(8192), K=2048 -> p_t[t][b] = sigmoid(.+bias)
  gemm_bt<1><<<dim3(64, 8), 256, 0, stream>>>(Wbf, Xbf, p_t, 2048, 8192, 8192, bias);
  tree_expand<<<1024, 256, 0, stream>>>(p_t, app_t);
  transpose_out<<<dim3(64, 32), 256, 0, stream>>>(app_t, p_t, all_pp, mu_out, mu_bf);
  // GEMM2: M=batch(8192), N=leafout(1024, mask 1000), K=1024 -> logits
  gemm_bt<0><<<dim3(8, 64), 256, 0, stream>>>(mu_bf, Wlbf, logits, 1024, 1000, 1000, nullptr);
  penalty_nodes<<<1023, 256, 0, stream>>>(app_t, p_t, pen);
}

// Round 5
// 353.972 us; speedup vs baseline: 1.2664x; 1.0671x over previous
//
#include <hip/hip_runtime.h>
#include <stdint.h>

// ---------------------------------------------------------------------------
// Soft Decision Tree forward: DEPTH=10, INPUT_DIM=2048, OUTPUT_DIM=1000,
// NUM_INNER=1023, NUM_LEAF=1024, BATCH=8192.
// Outputs (flat concat): logits[8192*1000], mu[8192*1024], penalty[1],
// all_pp[8192*2047].
//
// R7 = R5/R6 dbuf experiment, lambda-free rewrite (R5/R6 died on container
// infra twice; the closures were the only untested codegen surface vs the
// proven R2 kernel — removed). Schedule identical: double-buffered LDS,
// prefetch-next-subtile BEFORE compute, ONE __syncthreads per K-subtile so
// the auto vmcnt(0) drain lands after ~300cy of ds_read+MFMA.
// Pipeline: convert -> GEMM1(sigmoid) -> tree_expand -> transpose (R2) ->
// GEMM2 -> penalty_nodes.
// ---------------------------------------------------------------------------

typedef short bf16x8 __attribute__((ext_vector_type(8)));
typedef float f32x4  __attribute__((ext_vector_type(4)));

#define ASG __attribute__((address_space(1)))
#define ASL __attribute__((address_space(3)))

__device__ __forceinline__ void gl_lds16(const void* g, void* l) {
  // async global->LDS, 16B per lane; LDS dest is wave-uniform base + lane*16
  __builtin_amdgcn_global_load_lds((ASG void*)(uintptr_t)g, (ASL void*)l, 16, 0, 0);
}

__device__ __forceinline__ unsigned short f2bf(float x) {
  union { float f; unsigned u; } v; v.f = x;
  unsigned r = v.u + 0x7FFFu + ((v.u >> 16) & 1u);  // RNE
  return (unsigned short)(r >> 16);
}

// ---------------------------------------------------------------------------
// K0: conversions. Xbf (8192x2048 bf16), Wbf (1024x2048 bf16, row 1023 = 0),
// bias[1024] (W_inner col 0), Wlbf (1024x1024 bf16, rows >=1000 zero).
// Also zeros the penalty slot.
// ---------------------------------------------------------------------------
__global__ __launch_bounds__(256) void convert_kernel(
    const float* __restrict__ X, const float* __restrict__ Wi,
    const float* __restrict__ Wl, unsigned short* __restrict__ Xbf,
    unsigned short* __restrict__ Wbf, unsigned short* __restrict__ Wlbf,
    float* __restrict__ bias, float* __restrict__ pen)
{
  const int tid = blockIdx.x * 256 + threadIdx.x;
  const int stride = gridDim.x * 256;

  const float4* X4 = (const float4*)X;
  ushort4* Xb4 = (ushort4*)Xbf;
  for (int i = tid; i < (8192 * 2048) / 4; i += stride) {
    float4 v = X4[i];
    ushort4 o;
    o.x = f2bf(v.x); o.y = f2bf(v.y); o.z = f2bf(v.z); o.w = f2bf(v.w);
    Xb4[i] = o;
  }
  for (int i = tid; i < 1024 * 2048; i += stride) {
    int t = i >> 11, k = i & 2047;
    Wbf[i] = (t < 1023) ? f2bf(Wi[t * 2049 + 1 + k]) : (unsigned short)0;
  }
  for (int i = tid; i < 1024 * 1024; i += stride) {
    Wlbf[i] = (i < 1000 * 1024) ? f2bf(Wl[i]) : (unsigned short)0;
  }
  if (tid < 1024) bias[tid] = (tid < 1023) ? Wi[tid * 2049] : 0.0f;
  if (tid == 0) *pen = 0.0f;
}

// ---------------------------------------------------------------------------
// bf16 NT GEMM: C[m][n] = sum_k A[m][k]*B[n][k].
// 128x128 tile, BK=32, 4 waves of 4x4 16x16x32 MFMA.
// Double-buffered LDS; per K-subtile: {stage next -> other buf, ds_read+MFMA
// current buf, __syncthreads}. K must be a multiple of 64.
// EPI=1: C = sigmoid(acc + bias[m]), unconditional store (GEMM1 -> p_t).
// EPI=0: plain store masked to n < nmax (GEMM2 -> logits).
// ---------------------------------------------------------------------------
#define GEMM_COMPUTE(PA, PB)                                              \
  {                                                                       \
    bf16x8 af[4], bfv[4];                                                 \
    _Pragma("unroll")                                                     \
    for (int i = 0; i < 4; ++i)                                           \
      af[i] = *(const bf16x8*)&PA[(wm + i * 16 + lr) * 32 + lk];          \
    _Pragma("unroll")                                                     \
    for (int i = 0; i < 4; ++i)                                           \
      bfv[i] = *(const bf16x8*)&PB[(wn + i * 16 + lr) * 32 + lk];         \
    _Pragma("unroll")                                                     \
    for (int mi = 0; mi < 4; ++mi)                                        \
      _Pragma("unroll")                                                   \
      for (int ni = 0; ni < 4; ++ni)                                      \
        acc[mi][ni] = __builtin_amdgcn_mfma_f32_16x16x32_bf16(            \
            af[mi], bfv[ni], acc[mi][ni], 0, 0, 0);                       \
  }

template <int EPI>
__global__ __launch_bounds__(256) void gemm_bt(
    const unsigned short* __restrict__ A, const unsigned short* __restrict__ B,
    float* __restrict__ C, int K, int ldc, int nmax,
    const float* __restrict__ bias)
{
  __shared__ __align__(16) unsigned short sA0[128 * 32];
  __shared__ __align__(16) unsigned short sB0[128 * 32];
  __shared__ __align__(16) unsigned short sA1[128 * 32];
  __shared__ __align__(16) unsigned short sB1[128 * 32];

  const int tid  = threadIdx.x;
  const int lane = tid & 63;
  const int wv   = tid >> 6;
  const int wm   = (wv >> 1) * 64;
  const int wn   = (wv & 1) * 64;
  const int m0   = blockIdx.y * 128;
  const int n0   = blockIdx.x * 128;
  const int lr   = lane & 15;
  const int lk   = (lane >> 4) * 8;

  f32x4 acc[4][4] = {};

  const int chunk0 = wv * 64 + lane;
  const int crow   = chunk0 >> 2;         // 0..63
  const int coff   = (chunk0 & 3) * 8;    // element offset within row
  const unsigned short* ga0 = A + (size_t)(m0 + crow) * K + coff;
  const unsigned short* ga1 = A + (size_t)(m0 + crow + 64) * K + coff;
  const unsigned short* gb0 = B + (size_t)(n0 + crow) * K + coff;
  const unsigned short* gb1 = B + (size_t)(n0 + crow + 64) * K + coff;
  const int so0 = (wv * 64) * 8;          // wave-uniform LDS offsets
  const int so1 = (256 + wv * 64) * 8;

  // prologue: stage k=0 into buf0
  gl_lds16(ga0, sA0 + so0);
  gl_lds16(ga1, sA0 + so1);
  gl_lds16(gb0, sB0 + so0);
  gl_lds16(gb1, sB0 + so1);
  __syncthreads();  // buf0 ready (auto vmcnt(0)+lgkmcnt(0) drain)

  for (int k0 = 0; k0 < K; k0 += 64) {
    // phase A: prefetch k0+32 -> buf1 (always exists: k0 <= K-64); compute buf0
    gl_lds16(ga0 + k0 + 32, sA1 + so0);
    gl_lds16(ga1 + k0 + 32, sA1 + so1);
    gl_lds16(gb0 + k0 + 32, sB1 + so0);
    gl_lds16(gb1 + k0 + 32, sB1 + so1);
    GEMM_COMPUTE(sA0, sB0)
    __syncthreads();  // buf1 ready; all reads of buf0 drained
    // phase B: prefetch k0+64 -> buf0 (unless last); compute buf1
    if (k0 + 64 < K) {
      gl_lds16(ga0 + k0 + 64, sA0 + so0);
      gl_lds16(ga1 + k0 + 64, sA0 + so1);
      gl_lds16(gb0 + k0 + 64, sB0 + so0);
      gl_lds16(gb1 + k0 + 64, sB0 + so1);
    }
    GEMM_COMPUTE(sA1, sB1)
    __syncthreads();  // buf0 ready; all reads of buf1 drained
  }

  // epilogue: D[m][n], m = (lane>>4)*4 + r, n = lane&15
#pragma unroll
  for (int mi = 0; mi < 4; ++mi) {
#pragma unroll
    for (int ni = 0; ni < 4; ++ni) {
      const int mbase = m0 + wm + mi * 16 + (lane >> 4) * 4;
      const int n = n0 + wn + ni * 16 + lr;
#pragma unroll
      for (int r = 0; r < 4; ++r) {
        const int m = mbase + r;
        float v = acc[mi][ni][r];
        if (EPI == 1) {
          v += bias[m];
          v = 1.0f / (1.0f + __expf(-v));
          C[(size_t)m * ldc + n] = v;
        } else {
          if (n < nmax) C[(size_t)m * ldc + n] = v;
        }
      }
    }
  }
}

// ---------------------------------------------------------------------------
// Tree expansion over INNER nodes only (levels 0..9), transposed layout
// app_t[node][batch], heap-ordered. Pure mul+store walk — no reductions.
// Merged: blocks with subtree==0 also walk the top 31 nodes (levels 0..4).
// ---------------------------------------------------------------------------
template <int LVL, int MAXLVL>
__device__ __forceinline__ void walk(unsigned t, float mu,
                                     const float* __restrict__ p_t,
                                     float* __restrict__ app, unsigned b)
{
  app[t * 8192u + b] = mu;
  if constexpr (LVL < MAXLVL) {
    float p = p_t[t * 8192u + b];
    walk<LVL + 1, MAXLVL>(2u * t + 1u, mu * (1.0f - p), p_t, app, b);
    walk<LVL + 1, MAXLVL>(2u * t + 2u, mu * p, p_t, app, b);
  }
}

__global__ __launch_bounds__(256) void tree_expand(const float* __restrict__ p_t,
                                                   float* __restrict__ app)
{
  unsigned b = (blockIdx.x & 31u) * 256u + threadIdx.x;  // 0..8191
  unsigned s = blockIdx.x >> 5;                          // subtree 0..31
  if (s == 0) walk<0, 4>(0u, 1.0f, p_t, app, b);         // nodes 0..30
  unsigned t0 = 31u + s;                                 // level-5 root
  // recompute root mu from the 5 ancestors (rows are L2-resident)
  float mu = 1.0f;
  unsigned a = t0;
#pragma unroll
  for (int l = 0; l < 5; ++l) {
    unsigned par = (a - 1u) >> 1;
    float p = p_t[par * 8192u + b];
    mu *= (a & 1u) ? (1.0f - p) : p;   // odd = left child = (1-p)
    a = par;
  }
  walk<5, 9>(t0, mu, p_t, app, b);     // nodes 31..1022
}

// ---------------------------------------------------------------------------
// Transpose app_t (inner nodes) -> all_pp (8192x2047); leaves (t>=1023)
// recomputed from parent mu/p and additionally written to mu (8192x1024)
// and mu_bf (bf16, GEMM2 A operand).  (R2-proven 32x32 version.)
// ---------------------------------------------------------------------------
__global__ __launch_bounds__(256) void transpose_out(
    const float* __restrict__ app_t, const float* __restrict__ p_t,
    float* __restrict__ all_pp, float* __restrict__ mu_out,
    unsigned short* __restrict__ mu_bf)
{
  __shared__ float tile[32][33];
  const int b0 = blockIdx.x * 32;
  const int t0 = blockIdx.y * 32;
  const int tx = threadIdx.x;  // 0..31
  const int ty = threadIdx.y;  // 0..7

#pragma unroll
  for (int r = 0; r < 4; ++r) {
    int t = t0 + ty + r * 8;
    float v = 0.0f;
    if (t < 1023) {
      v = app_t[(size_t)t * 8192 + b0 + tx];
    } else if (t < 2047) {
      int u = (t - 1) >> 1;                       // parent (511..1022)
      float m = app_t[(size_t)u * 8192 + b0 + tx];
      float p = p_t[(size_t)u * 8192 + b0 + tx];
      v = (t & 1) ? m * (1.0f - p) : m * p;
    }
    tile[ty + r * 8][tx] = v;
  }
  __syncthreads();
#pragma unroll
  for (int r = 0; r < 4; ++r) {
    int b = b0 + ty + r * 8;
    int t = t0 + tx;
    if (t < 2047) {
      float v = tile[tx][ty + r * 8];
      all_pp[(size_t)b * 2047 + t] = v;
      if (t >= 1023) {
        int l = t - 1023;
        mu_out[(size_t)b * 1024 + l] = v;
        mu_bf[(size_t)b * 1024 + l] = f2bf(v);
      }
    }
  }
}

// ---------------------------------------------------------------------------
// Penalty: per inner node t, alpha = sum_b(p*mu)/sum_b(mu);
// pen_t = log(a)+log(1-a) (non-finite -> 0); penalty -= 0.5*2^-lvl * pen_t.
// Coalesced streaming over t-major rows (L3-warm); one atomic per block.
// ---------------------------------------------------------------------------
__global__ __launch_bounds__(256) void penalty_nodes(
    const float* __restrict__ app_t, const float* __restrict__ p_t,
    float* __restrict__ pen)
{
  const int t = blockIdx.x;  // 0..1022
  const float* mu = app_t + (size_t)t * 8192;
  const float* pp = p_t + (size_t)t * 8192;
  float num = 0.0f, den = 0.0f;
  for (int b = threadIdx.x; b < 8192; b += 256) {
    float m = mu[b];
    num += m * pp[b];
    den += m;
  }
#pragma unroll
  for (int o = 32; o; o >>= 1) {
    num += __shfl_down(num, o);
    den += __shfl_down(den, o);
  }
  __shared__ float sn[4], sd[4];
  if ((threadIdx.x & 63) == 0) {
    sn[threadIdx.x >> 6] = num;
    sd[threadIdx.x >> 6] = den;
  }
  __syncthreads();
  if (threadIdx.x == 0) {
    num = sn[0] + sn[1] + sn[2] + sn[3];
    den = sd[0] + sd[1] + sd[2] + sd[3];
    float a = num / den;
    float lg = __logf(a) + __logf(1.0f - a);
    if (!(lg > -1e30f && lg < 1e30f)) lg = 0.0f;  // NaN / +-inf -> 0
    int lvl = 31 - __clz(t + 1);
    float contrib = -0.5f * (1.0f / (float)(1 << lvl)) * lg;
    atomicAdd(pen, contrib);
  }
}

// ---------------------------------------------------------------------------
extern "C" void kernel_launch(void* const* d_in, const int* in_sizes, int n_in,
                              void* d_out, int out_size, void* d_ws,
                              size_t ws_size, hipStream_t stream)
{
  const float* X  = (const float*)d_in[0];  // 8192x2048
  const float* Wi = (const float*)d_in[1];  // 1023x2049
  const float* Wl = (const float*)d_in[2];  // 1000x1024
  float* out = (float*)d_out;

  char* ws = (char*)d_ws;
  // workspace layout (bytes):
  float* p_t            = (float*)(ws + 0);                  // 32 MB
  unsigned short* Xbf   = (unsigned short*)(ws + 33554432);  // 32 MB
  float* app_t          = (float*)(ws + 33554432);           // overlay, 32 MB
  unsigned short* mu_bf = (unsigned short*)(ws + 67108864);  // 16 MB
  unsigned short* Wbf   = (unsigned short*)(ws + 83886080);  // 4 MB
  unsigned short* Wlbf  = (unsigned short*)(ws + 88080384);  // 2 MB
  float* bias           = (float*)(ws + 90177536);           // 4 KB

  float* logits = out;                 // 8192*1000
  float* mu_out = out + 8192000;       // 8192*1024
  float* pen    = out + 16580608;      // 1
  float* all_pp = out + 16580609;      // 8192*2047

  convert_kernel<<<1024, 256, 0, stream>>>(X, Wi, Wl, Xbf, Wbf, Wlbf, bias, pen);
  // GEMM1: M=nodes(1024), N=batch(8192), K=2048 -> p_t[t][b] = sigmoid(.+bias)
  gemm_bt<1><<<dim3(64, 8), 256, 0, stream>>>(Wbf, Xbf, p_t, 2048, 8192, 8192, bias);
  tree_expand<<<1024, 256, 0, stream>>>(p_t, app_t);
  transpose_out<<<dim3(256, 64), dim3(32, 8), 0, stream>>>(app_t, p_t, all_pp, mu_out, mu_bf);
  // GEMM2: M=batch(8192), N=leafout(1024, mask 1000), K=1024 -> logits
  gemm_bt<0><<<dim3(8, 64), 256, 0, stream>>>(mu_bf, Wlbf, logits, 1024, 1000, 1000, nullptr);
  penalty_nodes<<<1023, 256, 0, stream>>>(app_t, p_t, pen);
}